// Round 15
// baseline (318.023 us; speedup 1.0000x reference)
//
#include <hip/hip_runtime.h>
#include <hip/hip_bf16.h>
#include <math.h>

#define N_NODES 20000
#define N_EDGES 160000
#define FIN 64
#define EDGE_DIM 8
#define H_HEADS 4
#define C_CH 128
#define HC 512
#define NUM_RELS 4
#define E_TOT (N_EDGES + N_NODES)   // 180000
#define E_PAD 320256                // >= sum of per-row 8-padded counts

typedef __bf16 bf16x8 __attribute__((ext_vector_type(8)));
typedef __bf16 bf16x4 __attribute__((ext_vector_type(4)));
typedef float f32x4 __attribute__((ext_vector_type(4)));
typedef unsigned short u16x8 __attribute__((ext_vector_type(8)));

// ---------- custom fill: zero counts+csr_src+den1+den2 (contiguous), csr_eid = -1 ----------
// zero block: counts(N) + csr_src(E_PAD) + den1(4N) + den2(4N) = 9N + E_PAD ints
#define NZ4 ((9 * N_NODES + E_PAD) / 4)   // 125064
#define NM4 (E_PAD / 4)                   // 80064
__global__ void k_fill(int4* __restrict__ zbase, int4* __restrict__ mbase) {
    int tid = blockIdx.x * 256 + threadIdx.x;
    if (tid < NZ4) {
        zbase[tid] = make_int4(0, 0, 0, 0);
    } else if (tid < NZ4 + NM4) {
        mbase[tid - NZ4] = make_int4(-1, -1, -1, -1);
    }
}

// ---------- merged prep: x cvt + tiled W1/W2 transposes + small precomputes ----------
#define NX4 (N_NODES * FIN / 4)          // 320000
#define XB  (NX4 / 256)                  // 1250 (exact)
#define W1B 8                            // W1: 64x512 -> 8 tiles of 64x64
#define W2B 64                           // W2: 512x512 -> 64 tiles
#define PREPB 19
__global__ void k_prep_all(const float* __restrict__ x, __bf16* __restrict__ xb,
                           const float* __restrict__ W1, __bf16* __restrict__ Wt1,
                           const float* __restrict__ W2, __bf16* __restrict__ Wt2,
                           const float* __restrict__ We1, const float* __restrict__ ae1,
                           const float* __restrict__ We2, const float* __restrict__ ae2,
                           float* __restrict__ q1, float* __restrict__ q2,
                           const float* __restrict__ Wd1, const float* __restrict__ Wd2,
                           const float* __restrict__ bd1, const float* __restrict__ bd2,
                           float* __restrict__ M, float* __restrict__ cvec,
                           const float* __restrict__ as1, const float* __restrict__ ad1,
                           float* __restrict__ w1as, float* __restrict__ w1ad) {
    __shared__ float tile[64][65];
    int bid = blockIdx.x;
    int t = threadIdx.x;
    if (bid < XB) {
        int tid = bid * 256 + t;
        float4 v = *(const float4*)(x + (size_t)tid * 4);
        __bf16 o[4] = {(__bf16)v.x, (__bf16)v.y, (__bf16)v.z, (__bf16)v.w};
        *(ushort2*)(xb + (size_t)tid * 4) = *(ushort2*)o;
        *(ushort2*)(xb + (size_t)tid * 4 + 2) = *(ushort2*)(o + 2);
        return;
    }
    if (bid < XB + W1B) {
        // W1 transpose tile: W1[64][512] -> Wt1[512][64]
        int tn = bid - XB;
        int rr = t >> 6, cc = t & 63;
        #pragma unroll
        for (int i = 0; i < 16; ++i) {
            int row = rr * 16 + i;
            tile[row][cc] = W1[(size_t)row * HC + tn * 64 + cc];
        }
        __syncthreads();
        #pragma unroll
        for (int i = 0; i < 16; ++i) {
            int row = rr * 16 + i;
            Wt1[(size_t)(tn * 64 + row) * 64 + cc] = (__bf16)tile[cc][row];
        }
        return;
    }
    if (bid < XB + W1B + W2B) {
        // W2 transpose tile: W2[512][512] -> Wt2[512][512]
        int p2 = bid - XB - W1B;
        int tk = p2 >> 3, tn = p2 & 7;
        int rr = t >> 6, cc = t & 63;
        #pragma unroll
        for (int i = 0; i < 16; ++i) {
            int row = rr * 16 + i;
            tile[row][cc] = W2[(size_t)(tk * 64 + row) * HC + tn * 64 + cc];
        }
        __syncthreads();
        #pragma unroll
        for (int i = 0; i < 16; ++i) {
            int row = rr * 16 + i;
            Wt2[(size_t)(tn * 64 + row) * HC + tk * 64 + cc] = (__bf16)tile[cc][row];
        }
        return;
    }
    int pb = bid - XB - W1B - W2B;     // 0..18
    if (pb == 16) {
        if (t >= 64) return;
        const float* We = (t < 32) ? We1 : We2;
        const float* ae = (t < 32) ? ae1 : ae2;
        float* q = (t < 32) ? q1 : q2;
        int i = t & 31, h = i >> 3, d = i & 7;
        float s = 0.f;
        for (int c = 0; c < 128; ++c) s += We[d * 512 + h * 128 + c] * ae[h * 128 + c];
        q[i] = s;
    } else if (pb == 17 || pb == 18) {
        int h = t >> 6, k = t & 63;
        const float* av = (pb == 17) ? as1 : ad1;
        float* outp = (pb == 17) ? w1as : w1ad;
        float s = 0.f;
        for (int c = 0; c < 128; ++c) s += W1[(size_t)k * HC + h * 128 + c] * av[h * 128 + c];
        outp[h * 64 + k] = s;
    } else {
        int tid = pb * 256 + t;   // < 4096
        int i = tid >> 2, r = tid & 3;
        float s = 0.f;
        for (int k = 0; k < 256; ++k) s += Wd1[i * 256 + k] * Wd2[k * 4 + r];
        M[tid] = s;
        if (tid < 4) {
            float c = 0.f;
            for (int k = 0; k < 256; ++k) c += bd1[k] * Wd2[k * 4 + tid];
            cvec[tid] = c + bd2[tid];
        }
    }
}

// ---------- bf16 MFMA GEMM (layer 2): head-major out + FUSED node alphas ----------
#define LDP 40
__global__ __launch_bounds__(256)
void k_gemm_bf16(const __bf16* __restrict__ A, const __bf16* __restrict__ Bt,
                 __bf16* __restrict__ Ch, int M, int K,
                 const float* __restrict__ a_s2, const float* __restrict__ a_d2,
                 float* __restrict__ as_, float* __restrict__ ad_) {
    __shared__ __bf16 As[128 * LDP];
    __shared__ __bf16 Bs[128 * LDP];

    int nwg = gridDim.x;
    int f = blockIdx.x;
    int q = nwg >> 3, r = nwg & 7;
    int xcd = f & 7, idx = f >> 3;
    int wg = (xcd < r ? xcd * (q + 1) : r * (q + 1) + (xcd - r) * q) + idx;
    int by = wg >> 2, bx = wg & 3;
    int br = by * 128, bc = bx * 128;

    const int t = threadIdx.x;
    const int lane = t & 63;
    const int wid = t >> 6;
    const int wr = wid >> 1, wc = wid & 1;
    const int l15 = lane & 15, lkg = lane >> 4;

    const int srow = t >> 1, shalf = (t & 1) * 16;
    const int agr = br + srow;
    const __bf16* Ap = A + (size_t)agr * K + shalf;
    const __bf16* Bp = Bt + (size_t)(bc + srow) * K + shalf;

    f32x4 acc[4][4] = {};

    for (int k0 = 0; k0 < K; k0 += 32) {
        u16x8 av0 = {}, av1 = {};
        if (agr < M) {
            av0 = *(const u16x8*)(Ap + k0);
            av1 = *(const u16x8*)(Ap + k0 + 8);
        }
        u16x8 bv0 = *(const u16x8*)(Bp + k0);
        u16x8 bv1 = *(const u16x8*)(Bp + k0 + 8);
        *(u16x8*)(As + srow * LDP + shalf) = av0;
        *(u16x8*)(As + srow * LDP + shalf + 8) = av1;
        *(u16x8*)(Bs + srow * LDP + shalf) = bv0;
        *(u16x8*)(Bs + srow * LDP + shalf + 8) = bv1;
        __syncthreads();

        bf16x8 a[4], b[4];
        #pragma unroll
        for (int m = 0; m < 4; ++m)
            a[m] = *(const bf16x8*)(As + (wr * 64 + m * 16 + l15) * LDP + lkg * 8);
        #pragma unroll
        for (int n = 0; n < 4; ++n)
            b[n] = *(const bf16x8*)(Bs + (wc * 64 + n * 16 + l15) * LDP + lkg * 8);
        #pragma unroll
        for (int m = 0; m < 4; ++m)
            #pragma unroll
            for (int n = 0; n < 4; ++n)
                acc[m][n] = __builtin_amdgcn_mfma_f32_16x16x32_bf16(a[m], b[n], acc[m][n], 0, 0, 0);
        __syncthreads();
    }

    // C-write (head-major)
    #pragma unroll
    for (int m = 0; m < 4; ++m) {
        int rbase = br + wr * 64 + m * 16 + lkg * 4;
        #pragma unroll
        for (int n = 0; n < 4; ++n) {
            int lcol = wc * 64 + n * 16 + l15;
            #pragma unroll
            for (int rg = 0; rg < 4; ++rg) {
                int gr = rbase + rg;
                if (gr < M)
                    Ch[((size_t)bx * N_NODES + gr) * 128 + lcol] = (__bf16)acc[m][n][rg];
            }
        }
    }

    // ---- fused alpha_src / alpha_dst for head bx ----
    float as_w[4], ad_w[4];
    #pragma unroll
    for (int n = 0; n < 4; ++n) {
        int col = wc * 64 + n * 16 + l15;
        as_w[n] = a_s2[bx * 128 + col];
        ad_w[n] = a_d2[bx * 128 + col];
    }
    float* sred = (float*)As;
    #pragma unroll
    for (int m = 0; m < 4; ++m) {
        #pragma unroll
        for (int rg = 0; rg < 4; ++rg) {
            float s = 0.f, d = 0.f;
            #pragma unroll
            for (int n = 0; n < 4; ++n) {
                float c = acc[m][n][rg];
                s += c * as_w[n];
                d += c * ad_w[n];
            }
            #pragma unroll
            for (int off = 1; off <= 8; off <<= 1) {
                s += __shfl_xor(s, off);
                d += __shfl_xor(d, off);
            }
            if (l15 == 0) {
                int lrow = wr * 64 + m * 16 + lkg * 4 + rg;
                sred[lrow * 2 + wc] = s;
                sred[256 + lrow * 2 + wc] = d;
            }
        }
    }
    __syncthreads();
    if (t < 128) {
        int gr = br + t;
        if (gr < M) {
            as_[gr * 4 + bx] = sred[t * 2] + sred[t * 2 + 1];
            ad_[gr * 4 + bx] = sred[256 + t * 2] + sred[256 + t * 2 + 1];
        }
    }
}

// ---------- layer-1 head GEMM: z1[n, h*128+c] = elu(agg[n,h,:]@W1h + b1) ----------
__global__ __launch_bounds__(256)
void k_gemm_head(const __bf16* __restrict__ aggb, const __bf16* __restrict__ Wt1,
                 const float* __restrict__ b1, __bf16* __restrict__ z1b, int M) {
    __shared__ __bf16 As[128 * LDP];
    __shared__ __bf16 Bs[128 * LDP];
    const int h = blockIdx.x;
    const int br = blockIdx.y * 128;

    const int t = threadIdx.x;
    const int lane = t & 63;
    const int wid = t >> 6;
    const int wr = wid >> 1, wc = wid & 1;
    const int l15 = lane & 15, lkg = lane >> 4;

    const int srow = t >> 1, shalf = (t & 1) * 16;
    const int agr = br + srow;
    const __bf16* Ap = aggb + (size_t)agr * 256 + h * 64 + shalf;
    const __bf16* Bp = Wt1 + (size_t)(h * 128 + srow) * 64 + shalf;

    f32x4 acc[4][4] = {};

    #pragma unroll
    for (int k0 = 0; k0 < 64; k0 += 32) {
        u16x8 av0 = {}, av1 = {};
        if (agr < M) {
            av0 = *(const u16x8*)(Ap + k0);
            av1 = *(const u16x8*)(Ap + k0 + 8);
        }
        u16x8 bv0 = *(const u16x8*)(Bp + k0);
        u16x8 bv1 = *(const u16x8*)(Bp + k0 + 8);
        *(u16x8*)(As + srow * LDP + shalf) = av0;
        *(u16x8*)(As + srow * LDP + shalf + 8) = av1;
        *(u16x8*)(Bs + srow * LDP + shalf) = bv0;
        *(u16x8*)(Bs + srow * LDP + shalf + 8) = bv1;
        __syncthreads();

        bf16x8 a[4], b[4];
        #pragma unroll
        for (int m = 0; m < 4; ++m)
            a[m] = *(const bf16x8*)(As + (wr * 64 + m * 16 + l15) * LDP + lkg * 8);
        #pragma unroll
        for (int n = 0; n < 4; ++n)
            b[n] = *(const bf16x8*)(Bs + (wc * 64 + n * 16 + l15) * LDP + lkg * 8);
        #pragma unroll
        for (int m = 0; m < 4; ++m)
            #pragma unroll
            for (int n = 0; n < 4; ++n)
                acc[m][n] = __builtin_amdgcn_mfma_f32_16x16x32_bf16(a[m], b[n], acc[m][n], 0, 0, 0);
        __syncthreads();
    }

    #pragma unroll
    for (int m = 0; m < 4; ++m) {
        int rbase = br + wr * 64 + m * 16 + lkg * 4;
        #pragma unroll
        for (int n = 0; n < 4; ++n) {
            int gcol = h * 128 + wc * 64 + n * 16 + l15;
            float bias = b1[gcol];
            #pragma unroll
            for (int rg = 0; rg < 4; ++rg) {
                int gr = rbase + rg;
                if (gr < M) {
                    float v = acc[m][n][rg] + bias;
                    v = (v > 0.f) ? v : expm1f(v);
                    z1b[(size_t)gr * HC + gcol] = (__bf16)v;
                }
            }
        }
    }
}

// ---------- CSR build (8-padded rows) ----------
__global__ void k_count(const int* __restrict__ ei, int* __restrict__ counts) {
    int e = blockIdx.x * 256 + threadIdx.x;
    if (e >= E_TOT) return;
    int dst = (e < N_EDGES) ? ei[N_EDGES + e] : (e - N_EDGES);
    atomicAdd(counts + dst, 1);
}

__global__ __launch_bounds__(1024)
void k_scan(const int* __restrict__ counts, int* __restrict__ row_start,
            int* __restrict__ nxt) {
    __shared__ int part[1024];
    int t = threadIdx.x;
    int base = t * 20;
    int pre[20];
    int s = 0;
    #pragma unroll
    for (int i = 0; i < 20; ++i) {
        int idx = base + i;
        int c = (idx < N_NODES) ? ((counts[idx] + 7) & ~7) : 0;   // pad to x8
        pre[i] = s; s += c;
    }
    part[t] = s;
    __syncthreads();
    for (int off = 1; off < 1024; off <<= 1) {
        int v = (t >= off) ? part[t - off] : 0;
        __syncthreads();
        part[t] += v;
        __syncthreads();
    }
    int excl = (t == 0) ? 0 : part[t - 1];
    #pragma unroll
    for (int i = 0; i < 20; ++i) {
        int idx = base + i;
        if (idx < N_NODES) { int v = excl + pre[i]; row_start[idx] = v; nxt[idx] = v; }
    }
    if (t == 1023) row_start[N_NODES] = part[1023];
}

__global__ void k_scatter(const int* __restrict__ ei, int* __restrict__ nxt,
                          int* __restrict__ csr_src, int* __restrict__ csr_eid,
                          int* __restrict__ csr_dst) {
    int e = blockIdx.x * 256 + threadIdx.x;
    if (e >= E_TOT) return;
    int src, dst;
    if (e < N_EDGES) { src = ei[e]; dst = ei[N_EDGES + e]; }
    else             { src = dst = e - N_EDGES; }
    int pos = atomicAdd(nxt + dst, 1);
    csr_src[pos] = src;
    csr_eid[pos] = e;
    csr_dst[pos] = dst;
}

// ---------- self-loop mean edge features ----------
__global__ void k_mean_csr(const int* __restrict__ row_start, const int* __restrict__ csr_eid,
                           const float* __restrict__ ef, float* __restrict__ meanf) {
    int n = blockIdx.x * 32 + (threadIdx.x >> 3);
    int d = threadIdx.x & 7;
    if (n >= N_NODES) return;
    int rs = row_start[n], re = row_start[n + 1];
    float s = 0.f; int c = 0;
    for (int i = rs; i < re; ++i) {
        unsigned eid = (unsigned)csr_eid[i];
        if (eid < N_EDGES) { s += ef[(size_t)eid * 8 + d]; ++c; }
    }
    meanf[n * 8 + d] = s / fmaxf((float)c, 1.f);
}

// ---------- layer-1 node alphas from x ----------
__global__ __launch_bounds__(256)
void k_nodeab(const __bf16* __restrict__ xb, const float* __restrict__ w1as,
              const float* __restrict__ w1ad, float* __restrict__ as_,
              float* __restrict__ ad_) {
    int n = blockIdx.x * 4 + (threadIdx.x >> 6);
    int lane = threadIdx.x & 63;
    if (n >= N_NODES) return;
    float xv = (float)xb[(size_t)n * 64 + lane];
    float s[4], d[4];
    #pragma unroll
    for (int h = 0; h < 4; ++h) {
        s[h] = xv * w1as[h * 64 + lane];
        d[h] = xv * w1ad[h * 64 + lane];
    }
    #pragma unroll
    for (int off = 32; off; off >>= 1) {
        #pragma unroll
        for (int h = 0; h < 4; ++h) {
            s[h] += __shfl_xor(s[h], off);
            d[h] += __shfl_xor(d[h], off);
        }
    }
    if (lane == 0) {
        *(float4*)(as_ + n * 4) = make_float4(s[0], s[1], s[2], s[3]);
        *(float4*)(ad_ + n * 4) = make_float4(d[0], d[1], d[2], d[3]);
    }
}

// ---------- per-slot edge exp(alpha) + atomic denominator; padding (-1) -> w=0 ----------
__global__ void k_edge_ex(const int* __restrict__ csr_src, const int* __restrict__ csr_dst,
                          const int* __restrict__ csr_eid, const float* __restrict__ ef,
                          const float* __restrict__ meanf, const float* __restrict__ q,
                          const float* __restrict__ as_, const float* __restrict__ ad_,
                          float* __restrict__ wbuf, float* __restrict__ den) {
    int i = blockIdx.x * 256 + threadIdx.x;
    if (i >= E_PAD) return;
    int eid = csr_eid[i];
    if (eid == -1) {
        *(float4*)(wbuf + (size_t)i * 4) = make_float4(0.f, 0.f, 0.f, 0.f);
        return;
    }
    int src = csr_src[i], dst = csr_dst[i];
    const float* fe = (eid < N_EDGES) ? (ef + (size_t)eid * 8)
                                      : (meanf + (size_t)(eid - N_EDGES) * 8);
    float f[8];
    #pragma unroll
    for (int d = 0; d < 8; ++d) f[d] = fe[d];
    float4 asv = *(const float4*)(as_ + src * 4);
    float4 adv = *(const float4*)(ad_ + dst * 4);
    const float* asp = &asv.x;
    const float* adp = &adv.x;
    float4 o;
    float* op = &o.x;
    #pragma unroll
    for (int h = 0; h < 4; ++h) {
        float ae = 0.f;
        #pragma unroll
        for (int d = 0; d < 8; ++d) ae += f[d] * q[h * 8 + d];
        float a = asp[h] + adp[h] + ae;
        a = (a > 0.f) ? a : 0.2f * a;
        op[h] = expf(a);
        atomicAdd(den + dst * 4 + h, op[h]);
    }
    *(float4*)(wbuf + (size_t)i * 4) = o;
}

// ---------- layer-1 gather in x-space (den precomputed) ----------
__global__ __launch_bounds__(256)
void k_gather1(const int* __restrict__ row_start, const int* __restrict__ csr_src,
               const float* __restrict__ wbuf, const __bf16* __restrict__ xb,
               const float* __restrict__ den1, __bf16* __restrict__ aggb) {
    int wv = threadIdx.x >> 6;
    int n = blockIdx.x * 4 + wv;
    int lane = threadIdx.x & 63;
    if (n >= N_NODES) return;
    int rs = row_start[n], re = row_start[n + 1];
    float acc[4] = {};

    for (int i = rs; i < re; i += 8) {
        unsigned short xr[8];
        float4 wr[8];
        #pragma unroll
        for (int p = 0; p < 8; ++p) {
            int sp = csr_src[i + p];
            xr[p] = *(const unsigned short*)(xb + (size_t)sp * 64 + lane);
            wr[p] = *(const float4*)(wbuf + (size_t)(i + p) * 4);
        }
        __builtin_amdgcn_sched_barrier(0);
        #pragma unroll
        for (int p = 0; p < 8; ++p) {
            float xv = (float)*(const __bf16*)&xr[p];
            acc[0] += wr[p].x * xv;
            acc[1] += wr[p].y * xv;
            acc[2] += wr[p].z * xv;
            acc[3] += wr[p].w * xv;
        }
    }
    float4 dv = *(const float4*)(den1 + n * 4);
    const float* dvp = &dv.x;
    #pragma unroll
    for (int h = 0; h < 4; ++h)
        aggb[(size_t)n * 256 + h * 64 + lane] = (__bf16)(acc[h] / dvp[h]);
}

// ---------- layer-2 per-head gather + FUSED decoder UV (den precomputed) ----------
__global__ __launch_bounds__(256)
void k_gather2h(const int* __restrict__ row_start, const int* __restrict__ csr_src,
                const float* __restrict__ wbuf, const __bf16* __restrict__ xph,
                const float* __restrict__ b2, const float* __restrict__ Mm,
                const float* __restrict__ den2,
                float* __restrict__ Up, float* __restrict__ Vp) {
    int h = blockIdx.y;
    int wv = threadIdx.x >> 6;
    int n = blockIdx.x * 4 + wv;
    int lane = threadIdx.x & 63;
    if (n >= N_NODES) return;
    int rs = row_start[n], re = row_start[n + 1];
    const __bf16* xbase = xph + (size_t)h * N_NODES * 128 + lane * 2;
    float a0 = 0.f, a1 = 0.f;

    int i = rs;
    for (; i + 16 <= re; i += 16) {
        unsigned xr[16];
        float wr[16];
        #pragma unroll
        for (int p = 0; p < 16; ++p) {
            int sp = csr_src[i + p];
            wr[p] = wbuf[(size_t)(i + p) * 4 + h];
            xr[p] = *(const unsigned*)(xbase + (size_t)sp * 128);
        }
        __builtin_amdgcn_sched_barrier(0);
        #pragma unroll
        for (int p = 0; p < 16; ++p) {
            __bf16 b0 = *(const __bf16*)&xr[p];
            __bf16 b1v = *((const __bf16*)&xr[p] + 1);
            a0 += wr[p] * (float)b0;
            a1 += wr[p] * (float)b1v;
        }
    }
    for (; i < re; i += 8) {
        unsigned xr[8];
        float wr[8];
        #pragma unroll
        for (int p = 0; p < 8; ++p) {
            int sp = csr_src[i + p];
            wr[p] = wbuf[(size_t)(i + p) * 4 + h];
            xr[p] = *(const unsigned*)(xbase + (size_t)sp * 128);
        }
        __builtin_amdgcn_sched_barrier(0);
        #pragma unroll
        for (int p = 0; p < 8; ++p) {
            __bf16 b0 = *(const __bf16*)&xr[p];
            __bf16 b1v = *((const __bf16*)&xr[p] + 1);
            a0 += wr[p] * (float)b0;
            a1 += wr[p] * (float)b1v;
        }
    }
    float inv = 1.f / den2[n * 4 + h];
    float v0 = a0 * inv + b2[h * 128 + lane * 2];
    float v1 = a1 * inv + b2[h * 128 + lane * 2 + 1];
    v0 = (v0 > 0.f) ? v0 : expm1f(v0);
    v1 = (v1 > 0.f) ? v1 : expm1f(v1);

    // fused decoder: per-head partial U/V
    const float* m0 = Mm + (h * 128 + lane * 2) * 4;
    const float* n0 = Mm + 2048 + (h * 128 + lane * 2) * 4;
    float up[4], vp[4];
    #pragma unroll
    for (int r = 0; r < 4; ++r) {
        up[r] = v0 * m0[r] + v1 * m0[4 + r];
        vp[r] = v0 * n0[r] + v1 * n0[4 + r];
    }
    #pragma unroll
    for (int off = 32; off; off >>= 1) {
        #pragma unroll
        for (int r = 0; r < 4; ++r) {
            up[r] += __shfl_xor(up[r], off);
            vp[r] += __shfl_xor(vp[r], off);
        }
    }
    if (lane == 0) {
        *(float4*)(Up + ((size_t)h * N_NODES + n) * 4) = make_float4(up[0], up[1], up[2], up[3]);
        *(float4*)(Vp + ((size_t)h * N_NODES + n) * 4) = make_float4(vp[0], vp[1], vp[2], vp[3]);
    }
}

// ---------- per-edge output: sum 4 head-partials + sigmoid ----------
__global__ void k_edge_out(const int* __restrict__ ei, const float* __restrict__ Up,
                           const float* __restrict__ Vp, const float* __restrict__ cvec,
                           float* __restrict__ out) {
    int e = blockIdx.x * 256 + threadIdx.x;
    if (e >= N_EDGES) return;
    int s = ei[e], d = ei[N_EDGES + e];
    float4 u = make_float4(0.f, 0.f, 0.f, 0.f);
    float4 v = make_float4(0.f, 0.f, 0.f, 0.f);
    #pragma unroll
    for (int h = 0; h < 4; ++h) {
        float4 uh = *(const float4*)(Up + ((size_t)h * N_NODES + s) * 4);
        float4 vh = *(const float4*)(Vp + ((size_t)h * N_NODES + d) * 4);
        u.x += uh.x; u.y += uh.y; u.z += uh.z; u.w += uh.w;
        v.x += vh.x; v.y += vh.y; v.z += vh.z; v.w += vh.w;
    }
    float4 c = *(const float4*)cvec;
    float4 o;
    o.x = 1.f / (1.f + expf(-(u.x + v.x + c.x)));
    o.y = 1.f / (1.f + expf(-(u.y + v.y + c.y)));
    o.z = 1.f / (1.f + expf(-(u.z + v.z + c.z)));
    o.w = 1.f / (1.f + expf(-(u.w + v.w + c.w)));
    *(float4*)(out + (size_t)e * 4) = o;
}

extern "C" void kernel_launch(void* const* d_in, const int* in_sizes, int n_in,
                              void* d_out, int out_size, void* d_ws, size_t ws_size,
                              hipStream_t stream) {
    (void)in_sizes; (void)n_in; (void)out_size; (void)ws_size;
    const float* x      = (const float*)d_in[0];
    const int*   ei     = (const int*)d_in[1];
    const float* ef     = (const float*)d_in[2];
    const float* W1     = (const float*)d_in[3];
    const float* a_src1 = (const float*)d_in[4];
    const float* a_dst1 = (const float*)d_in[5];
    const float* We1    = (const float*)d_in[6];
    const float* a_e1   = (const float*)d_in[7];
    const float* b1     = (const float*)d_in[8];
    const float* W2     = (const float*)d_in[9];
    const float* a_src2 = (const float*)d_in[10];
    const float* a_dst2 = (const float*)d_in[11];
    const float* We2    = (const float*)d_in[12];
    const float* a_e2   = (const float*)d_in[13];
    const float* b2     = (const float*)d_in[14];
    const float* Wd1    = (const float*)d_in[15];
    const float* bd1    = (const float*)d_in[16];
    const float* Wd2    = (const float*)d_in[17];
    const float* bd2    = (const float*)d_in[18];
    float* out = (float*)d_out;

    // workspace layout
    float* wbuf   = (float*)d_ws;                            // E_PAD*4
    float* as_    = wbuf + (size_t)E_PAD * 4;                // N*4
    float* ad_    = as_ + N_NODES * 4;                       // N*4
    float* meanf  = ad_ + N_NODES * 4;                       // N*8
    float* q1     = meanf + N_NODES * 8;                     // 32
    float* q2     = q1 + 32;                                 // 32
    float* w1as   = q2 + 32;                                 // 256
    float* w1ad   = w1as + 256;                              // 256
    float* Mm     = w1ad + 256;                              // 4096
    float* cv     = Mm + 4096;                               // 4
    float* Up     = cv + 4;                                  // 4*N*4
    float* Vp     = Up + (size_t)N_NODES * 16;               // 4*N*4
    int* row_start = (int*)(Vp + (size_t)N_NODES * 16);      // 20004
    int* nxt       = row_start + 20004;                      // N
    // ---- contiguous zero block (k_fill) ----
    int* counts    = nxt + N_NODES;                          // N
    int* csr_src   = counts + N_NODES;                       // E_PAD
    float* den1    = (float*)(csr_src + E_PAD);              // N*4
    float* den2    = den1 + N_NODES * 4;                     // N*4
    // ---- -1 block (k_fill) ----
    int* csr_eid   = (int*)(den2 + N_NODES * 4);             // E_PAD
    int* csr_dst   = csr_eid + E_PAD;                        // E_PAD
    __bf16* xb   = (__bf16*)(csr_dst + E_PAD);               // N*64
    __bf16* aggb = xb + (size_t)N_NODES * FIN;               // N*256
    __bf16* z1b  = aggb + (size_t)N_NODES * 256;             // N*512
    __bf16* xph2 = z1b + (size_t)N_NODES * HC;               // N*512 head-major
    __bf16* Wt1  = xph2 + (size_t)N_NODES * HC;              // 512*64
    __bf16* Wt2  = Wt1 + HC * FIN;                           // 512*512

    // ---- prep ----
    k_fill<<<(NZ4 + NM4 + 255) / 256, 256, 0, stream>>>((int4*)counts, (int4*)csr_eid);
    k_count<<<(E_TOT + 255) / 256, 256, 0, stream>>>(ei, counts);
    k_scan<<<1, 1024, 0, stream>>>(counts, row_start, nxt);
    k_scatter<<<(E_TOT + 255) / 256, 256, 0, stream>>>(ei, nxt, csr_src, csr_eid, csr_dst);
    k_mean_csr<<<(N_NODES + 31) / 32, 256, 0, stream>>>(row_start, csr_eid, ef, meanf);
    k_prep_all<<<XB + W1B + W2B + PREPB, 256, 0, stream>>>(x, xb, W1, Wt1, W2, Wt2,
                                                           We1, a_e1, We2, a_e2, q1, q2,
                                                           Wd1, Wd2, bd1, bd2, Mm, cv,
                                                           a_src1, a_dst1, w1as, w1ad);

    const int nblk = (N_NODES + 3) / 4;      // 5000
    const int nby = (N_NODES + 127) / 128;   // 157

    // ---- layer 1 (xp never materialized) ----
    k_nodeab<<<nblk, 256, 0, stream>>>(xb, w1as, w1ad, as_, ad_);
    k_edge_ex<<<(E_PAD + 255) / 256, 256, 0, stream>>>(csr_src, csr_dst, csr_eid, ef, meanf,
                                                       q1, as_, ad_, wbuf, den1);
    k_gather1<<<nblk, 256, 0, stream>>>(row_start, csr_src, wbuf, xb, den1, aggb);
    k_gemm_head<<<dim3(4, nby), 256, 0, stream>>>(aggb, Wt1, b1, z1b, N_NODES);

    // ---- layer 2 (node alphas fused into GEMM epilogue) ----
    k_gemm_bf16<<<nby * 4, 256, 0, stream>>>(z1b, Wt2, xph2, N_NODES, HC,
                                             a_src2, a_dst2, as_, ad_);
    k_edge_ex<<<(E_PAD + 255) / 256, 256, 0, stream>>>(csr_src, csr_dst, csr_eid, ef, meanf,
                                                       q2, as_, ad_, wbuf, den2);
    k_gather2h<<<dim3(nblk, 4), 256, 0, stream>>>(row_start, csr_src, wbuf, xph2, b2,
                                                  Mm, den2, Up, Vp);

    // ---- output ----
    k_edge_out<<<(N_EDGES + 255) / 256, 256, 0, stream>>>(ei, Up, Vp, cv, out);
}

// Round 16
// 230.797 us; speedup vs baseline: 1.3779x; 1.3779x over previous
//
#include <hip/hip_runtime.h>
#include <hip/hip_bf16.h>
#include <math.h>

#define N_NODES 20000
#define N_EDGES 160000
#define FIN 64
#define EDGE_DIM 8
#define H_HEADS 4
#define C_CH 128
#define HC 512
#define NUM_RELS 4
#define E_TOT (N_EDGES + N_NODES)   // 180000
#define E_PAD 320256                // >= sum of per-row 8-padded counts

typedef __bf16 bf16x8 __attribute__((ext_vector_type(8)));
typedef __bf16 bf16x4 __attribute__((ext_vector_type(4)));
typedef float f32x4 __attribute__((ext_vector_type(4)));
typedef unsigned short u16x8 __attribute__((ext_vector_type(8)));

// ---------- custom fill: zero counts+csr_src (contiguous), csr_eid = -1 ----------
#define NZ4 ((N_NODES + E_PAD) / 4)
#define NM4 (E_PAD / 4)
__global__ void k_fill(int4* __restrict__ zbase, int4* __restrict__ mbase) {
    int tid = blockIdx.x * 256 + threadIdx.x;
    if (tid < NZ4) {
        zbase[tid] = make_int4(0, 0, 0, 0);
    } else if (tid < NZ4 + NM4) {
        mbase[tid - NZ4] = make_int4(-1, -1, -1, -1);
    }
}

// ---------- merged prep: x cvt + tiled W1/W2 transposes + small precomputes ----------
#define NX4 (N_NODES * FIN / 4)          // 320000
#define XB  (NX4 / 256)                  // 1250 (exact)
#define W1B 8                            // W1: 64x512 -> 8 tiles of 64x64
#define W2B 64                           // W2: 512x512 -> 64 tiles
#define PREPB 19
__global__ void k_prep_all(const float* __restrict__ x, __bf16* __restrict__ xb,
                           const float* __restrict__ W1, __bf16* __restrict__ Wt1,
                           const float* __restrict__ W2, __bf16* __restrict__ Wt2,
                           const float* __restrict__ We1, const float* __restrict__ ae1,
                           const float* __restrict__ We2, const float* __restrict__ ae2,
                           float* __restrict__ q1, float* __restrict__ q2,
                           const float* __restrict__ Wd1, const float* __restrict__ Wd2,
                           const float* __restrict__ bd1, const float* __restrict__ bd2,
                           float* __restrict__ M, float* __restrict__ cvec,
                           const float* __restrict__ as1, const float* __restrict__ ad1,
                           float* __restrict__ w1as, float* __restrict__ w1ad) {
    __shared__ float tile[64][65];
    int bid = blockIdx.x;
    int t = threadIdx.x;
    if (bid < XB) {
        int tid = bid * 256 + t;
        float4 v = *(const float4*)(x + (size_t)tid * 4);
        __bf16 o[4] = {(__bf16)v.x, (__bf16)v.y, (__bf16)v.z, (__bf16)v.w};
        *(ushort2*)(xb + (size_t)tid * 4) = *(ushort2*)o;
        *(ushort2*)(xb + (size_t)tid * 4 + 2) = *(ushort2*)(o + 2);
        return;
    }
    if (bid < XB + W1B) {
        // W1 transpose tile: W1[64][512] -> Wt1[512][64]
        int tn = bid - XB;
        int rr = t >> 6, cc = t & 63;
        #pragma unroll
        for (int i = 0; i < 16; ++i) {
            int row = rr * 16 + i;
            tile[row][cc] = W1[(size_t)row * HC + tn * 64 + cc];
        }
        __syncthreads();
        #pragma unroll
        for (int i = 0; i < 16; ++i) {
            int row = rr * 16 + i;
            Wt1[(size_t)(tn * 64 + row) * 64 + cc] = (__bf16)tile[cc][row];
        }
        return;
    }
    if (bid < XB + W1B + W2B) {
        // W2 transpose tile: W2[512][512] -> Wt2[512][512]
        int p2 = bid - XB - W1B;
        int tk = p2 >> 3, tn = p2 & 7;
        int rr = t >> 6, cc = t & 63;
        #pragma unroll
        for (int i = 0; i < 16; ++i) {
            int row = rr * 16 + i;
            tile[row][cc] = W2[(size_t)(tk * 64 + row) * HC + tn * 64 + cc];
        }
        __syncthreads();
        #pragma unroll
        for (int i = 0; i < 16; ++i) {
            int row = rr * 16 + i;
            Wt2[(size_t)(tn * 64 + row) * HC + tk * 64 + cc] = (__bf16)tile[cc][row];
        }
        return;
    }
    int pb = bid - XB - W1B - W2B;     // 0..18
    if (pb == 16) {
        if (t >= 64) return;
        const float* We = (t < 32) ? We1 : We2;
        const float* ae = (t < 32) ? ae1 : ae2;
        float* q = (t < 32) ? q1 : q2;
        int i = t & 31, h = i >> 3, d = i & 7;
        float s = 0.f;
        for (int c = 0; c < 128; ++c) s += We[d * 512 + h * 128 + c] * ae[h * 128 + c];
        q[i] = s;
    } else if (pb == 17 || pb == 18) {
        int h = t >> 6, k = t & 63;
        const float* av = (pb == 17) ? as1 : ad1;
        float* outp = (pb == 17) ? w1as : w1ad;
        float s = 0.f;
        for (int c = 0; c < 128; ++c) s += W1[(size_t)k * HC + h * 128 + c] * av[h * 128 + c];
        outp[h * 64 + k] = s;
    } else {
        int tid = pb * 256 + t;   // < 4096
        int i = tid >> 2, r = tid & 3;
        float s = 0.f;
        for (int k = 0; k < 256; ++k) s += Wd1[i * 256 + k] * Wd2[k * 4 + r];
        M[tid] = s;
        if (tid < 4) {
            float c = 0.f;
            for (int k = 0; k < 256; ++k) c += bd1[k] * Wd2[k * 4 + tid];
            cvec[tid] = c + bd2[tid];
        }
    }
}

// ---------- bf16 MFMA GEMM (layer 2): head-major out + FUSED node alphas ----------
#define LDP 40
__global__ __launch_bounds__(256)
void k_gemm_bf16(const __bf16* __restrict__ A, const __bf16* __restrict__ Bt,
                 __bf16* __restrict__ Ch, int M, int K,
                 const float* __restrict__ a_s2, const float* __restrict__ a_d2,
                 float* __restrict__ as_, float* __restrict__ ad_) {
    __shared__ __bf16 As[128 * LDP];
    __shared__ __bf16 Bs[128 * LDP];

    int nwg = gridDim.x;
    int f = blockIdx.x;
    int q = nwg >> 3, r = nwg & 7;
    int xcd = f & 7, idx = f >> 3;
    int wg = (xcd < r ? xcd * (q + 1) : r * (q + 1) + (xcd - r) * q) + idx;
    int by = wg >> 2, bx = wg & 3;
    int br = by * 128, bc = bx * 128;

    const int t = threadIdx.x;
    const int lane = t & 63;
    const int wid = t >> 6;
    const int wr = wid >> 1, wc = wid & 1;
    const int l15 = lane & 15, lkg = lane >> 4;

    const int srow = t >> 1, shalf = (t & 1) * 16;
    const int agr = br + srow;
    const __bf16* Ap = A + (size_t)agr * K + shalf;
    const __bf16* Bp = Bt + (size_t)(bc + srow) * K + shalf;

    f32x4 acc[4][4] = {};

    for (int k0 = 0; k0 < K; k0 += 32) {
        u16x8 av0 = {}, av1 = {};
        if (agr < M) {
            av0 = *(const u16x8*)(Ap + k0);
            av1 = *(const u16x8*)(Ap + k0 + 8);
        }
        u16x8 bv0 = *(const u16x8*)(Bp + k0);
        u16x8 bv1 = *(const u16x8*)(Bp + k0 + 8);
        *(u16x8*)(As + srow * LDP + shalf) = av0;
        *(u16x8*)(As + srow * LDP + shalf + 8) = av1;
        *(u16x8*)(Bs + srow * LDP + shalf) = bv0;
        *(u16x8*)(Bs + srow * LDP + shalf + 8) = bv1;
        __syncthreads();

        bf16x8 a[4], b[4];
        #pragma unroll
        for (int m = 0; m < 4; ++m)
            a[m] = *(const bf16x8*)(As + (wr * 64 + m * 16 + l15) * LDP + lkg * 8);
        #pragma unroll
        for (int n = 0; n < 4; ++n)
            b[n] = *(const bf16x8*)(Bs + (wc * 64 + n * 16 + l15) * LDP + lkg * 8);
        #pragma unroll
        for (int m = 0; m < 4; ++m)
            #pragma unroll
            for (int n = 0; n < 4; ++n)
                acc[m][n] = __builtin_amdgcn_mfma_f32_16x16x32_bf16(a[m], b[n], acc[m][n], 0, 0, 0);
        __syncthreads();
    }

    // C-write (head-major)
    #pragma unroll
    for (int m = 0; m < 4; ++m) {
        int rbase = br + wr * 64 + m * 16 + lkg * 4;
        #pragma unroll
        for (int n = 0; n < 4; ++n) {
            int lcol = wc * 64 + n * 16 + l15;
            #pragma unroll
            for (int rg = 0; rg < 4; ++rg) {
                int gr = rbase + rg;
                if (gr < M)
                    Ch[((size_t)bx * N_NODES + gr) * 128 + lcol] = (__bf16)acc[m][n][rg];
            }
        }
    }

    // ---- fused alpha_src / alpha_dst for head bx ----
    float as_w[4], ad_w[4];
    #pragma unroll
    for (int n = 0; n < 4; ++n) {
        int col = wc * 64 + n * 16 + l15;
        as_w[n] = a_s2[bx * 128 + col];
        ad_w[n] = a_d2[bx * 128 + col];
    }
    float* sred = (float*)As;   // 512 floats scratch
    #pragma unroll
    for (int m = 0; m < 4; ++m) {
        #pragma unroll
        for (int rg = 0; rg < 4; ++rg) {
            float s = 0.f, d = 0.f;
            #pragma unroll
            for (int n = 0; n < 4; ++n) {
                float c = acc[m][n][rg];
                s += c * as_w[n];
                d += c * ad_w[n];
            }
            #pragma unroll
            for (int off = 1; off <= 8; off <<= 1) {
                s += __shfl_xor(s, off);
                d += __shfl_xor(d, off);
            }
            if (l15 == 0) {
                int lrow = wr * 64 + m * 16 + lkg * 4 + rg;
                sred[lrow * 2 + wc] = s;
                sred[256 + lrow * 2 + wc] = d;
            }
        }
    }
    __syncthreads();
    if (t < 128) {
        int gr = br + t;
        if (gr < M) {
            as_[gr * 4 + bx] = sred[t * 2] + sred[t * 2 + 1];
            ad_[gr * 4 + bx] = sred[256 + t * 2] + sred[256 + t * 2 + 1];
        }
    }
}

// ---------- layer-1 head GEMM: z1[n, h*128+c] = elu(agg[n,h,:]@W1h + b1) ----------
__global__ __launch_bounds__(256)
void k_gemm_head(const __bf16* __restrict__ aggb, const __bf16* __restrict__ Wt1,
                 const float* __restrict__ b1, __bf16* __restrict__ z1b, int M) {
    __shared__ __bf16 As[128 * LDP];
    __shared__ __bf16 Bs[128 * LDP];
    const int h = blockIdx.x;
    const int br = blockIdx.y * 128;

    const int t = threadIdx.x;
    const int lane = t & 63;
    const int wid = t >> 6;
    const int wr = wid >> 1, wc = wid & 1;
    const int l15 = lane & 15, lkg = lane >> 4;

    const int srow = t >> 1, shalf = (t & 1) * 16;
    const int agr = br + srow;
    const __bf16* Ap = aggb + (size_t)agr * 256 + h * 64 + shalf;
    const __bf16* Bp = Wt1 + (size_t)(h * 128 + srow) * 64 + shalf;

    f32x4 acc[4][4] = {};

    #pragma unroll
    for (int k0 = 0; k0 < 64; k0 += 32) {
        u16x8 av0 = {}, av1 = {};
        if (agr < M) {
            av0 = *(const u16x8*)(Ap + k0);
            av1 = *(const u16x8*)(Ap + k0 + 8);
        }
        u16x8 bv0 = *(const u16x8*)(Bp + k0);
        u16x8 bv1 = *(const u16x8*)(Bp + k0 + 8);
        *(u16x8*)(As + srow * LDP + shalf) = av0;
        *(u16x8*)(As + srow * LDP + shalf + 8) = av1;
        *(u16x8*)(Bs + srow * LDP + shalf) = bv0;
        *(u16x8*)(Bs + srow * LDP + shalf + 8) = bv1;
        __syncthreads();

        bf16x8 a[4], b[4];
        #pragma unroll
        for (int m = 0; m < 4; ++m)
            a[m] = *(const bf16x8*)(As + (wr * 64 + m * 16 + l15) * LDP + lkg * 8);
        #pragma unroll
        for (int n = 0; n < 4; ++n)
            b[n] = *(const bf16x8*)(Bs + (wc * 64 + n * 16 + l15) * LDP + lkg * 8);
        #pragma unroll
        for (int m = 0; m < 4; ++m)
            #pragma unroll
            for (int n = 0; n < 4; ++n)
                acc[m][n] = __builtin_amdgcn_mfma_f32_16x16x32_bf16(a[m], b[n], acc[m][n], 0, 0, 0);
        __syncthreads();
    }

    #pragma unroll
    for (int m = 0; m < 4; ++m) {
        int rbase = br + wr * 64 + m * 16 + lkg * 4;
        #pragma unroll
        for (int n = 0; n < 4; ++n) {
            int gcol = h * 128 + wc * 64 + n * 16 + l15;
            float bias = b1[gcol];
            #pragma unroll
            for (int rg = 0; rg < 4; ++rg) {
                int gr = rbase + rg;
                if (gr < M) {
                    float v = acc[m][n][rg] + bias;
                    v = (v > 0.f) ? v : expm1f(v);
                    z1b[(size_t)gr * HC + gcol] = (__bf16)v;
                }
            }
        }
    }
}

// ---------- CSR build (8-padded rows) ----------
__global__ void k_count(const int* __restrict__ ei, int* __restrict__ counts) {
    int e = blockIdx.x * 256 + threadIdx.x;
    if (e >= E_TOT) return;
    int dst = (e < N_EDGES) ? ei[N_EDGES + e] : (e - N_EDGES);
    atomicAdd(counts + dst, 1);
}

__global__ __launch_bounds__(1024)
void k_scan(const int* __restrict__ counts, int* __restrict__ row_start,
            int* __restrict__ nxt) {
    __shared__ int part[1024];
    int t = threadIdx.x;
    int base = t * 20;
    int pre[20];
    int s = 0;
    #pragma unroll
    for (int i = 0; i < 20; ++i) {
        int idx = base + i;
        int c = (idx < N_NODES) ? ((counts[idx] + 7) & ~7) : 0;   // pad to x8
        pre[i] = s; s += c;
    }
    part[t] = s;
    __syncthreads();
    for (int off = 1; off < 1024; off <<= 1) {
        int v = (t >= off) ? part[t - off] : 0;
        __syncthreads();
        part[t] += v;
        __syncthreads();
    }
    int excl = (t == 0) ? 0 : part[t - 1];
    #pragma unroll
    for (int i = 0; i < 20; ++i) {
        int idx = base + i;
        if (idx < N_NODES) { int v = excl + pre[i]; row_start[idx] = v; nxt[idx] = v; }
    }
    if (t == 1023) row_start[N_NODES] = part[1023];
}

__global__ void k_scatter(const int* __restrict__ ei, int* __restrict__ nxt,
                          int* __restrict__ csr_src, int* __restrict__ csr_eid,
                          int* __restrict__ csr_dst) {
    int e = blockIdx.x * 256 + threadIdx.x;
    if (e >= E_TOT) return;
    int src, dst;
    if (e < N_EDGES) { src = ei[e]; dst = ei[N_EDGES + e]; }
    else             { src = dst = e - N_EDGES; }
    int pos = atomicAdd(nxt + dst, 1);
    csr_src[pos] = src;
    csr_eid[pos] = e;
    csr_dst[pos] = dst;
}

// ---------- self-loop mean edge features ----------
__global__ void k_mean_csr(const int* __restrict__ row_start, const int* __restrict__ csr_eid,
                           const float* __restrict__ ef, float* __restrict__ meanf) {
    int n = blockIdx.x * 32 + (threadIdx.x >> 3);
    int d = threadIdx.x & 7;
    if (n >= N_NODES) return;
    int rs = row_start[n], re = row_start[n + 1];
    float s = 0.f; int c = 0;
    for (int i = rs; i < re; ++i) {
        unsigned eid = (unsigned)csr_eid[i];
        if (eid < N_EDGES) { s += ef[(size_t)eid * 8 + d]; ++c; }
    }
    meanf[n * 8 + d] = s / fmaxf((float)c, 1.f);
}

// ---------- layer-1 node alphas from x ----------
__global__ __launch_bounds__(256)
void k_nodeab(const __bf16* __restrict__ xb, const float* __restrict__ w1as,
              const float* __restrict__ w1ad, float* __restrict__ as_,
              float* __restrict__ ad_) {
    int n = blockIdx.x * 4 + (threadIdx.x >> 6);
    int lane = threadIdx.x & 63;
    if (n >= N_NODES) return;
    float xv = (float)xb[(size_t)n * 64 + lane];
    float s[4], d[4];
    #pragma unroll
    for (int h = 0; h < 4; ++h) {
        s[h] = xv * w1as[h * 64 + lane];
        d[h] = xv * w1ad[h * 64 + lane];
    }
    #pragma unroll
    for (int off = 32; off; off >>= 1) {
        #pragma unroll
        for (int h = 0; h < 4; ++h) {
            s[h] += __shfl_xor(s[h], off);
            d[h] += __shfl_xor(d[h], off);
        }
    }
    if (lane == 0) {
        *(float4*)(as_ + n * 4) = make_float4(s[0], s[1], s[2], s[3]);
        *(float4*)(ad_ + n * 4) = make_float4(d[0], d[1], d[2], d[3]);
    }
}

// ---------- per-slot edge exp(alpha); padding (-1) -> w=0 ----------
__global__ void k_edge_ex(const int* __restrict__ csr_src, const int* __restrict__ csr_dst,
                          const int* __restrict__ csr_eid, const float* __restrict__ ef,
                          const float* __restrict__ meanf, const float* __restrict__ q,
                          const float* __restrict__ as_, const float* __restrict__ ad_,
                          float* __restrict__ wbuf) {
    int i = blockIdx.x * 256 + threadIdx.x;
    if (i >= E_PAD) return;
    int eid = csr_eid[i];
    if (eid == -1) {
        *(float4*)(wbuf + (size_t)i * 4) = make_float4(0.f, 0.f, 0.f, 0.f);
        return;
    }
    int src = csr_src[i], dst = csr_dst[i];
    const float* fe = (eid < N_EDGES) ? (ef + (size_t)eid * 8)
                                      : (meanf + (size_t)(eid - N_EDGES) * 8);
    float f[8];
    #pragma unroll
    for (int d = 0; d < 8; ++d) f[d] = fe[d];
    float4 asv = *(const float4*)(as_ + src * 4);
    float4 adv = *(const float4*)(ad_ + dst * 4);
    const float* asp = &asv.x;
    const float* adp = &adv.x;
    float4 o;
    float* op = &o.x;
    #pragma unroll
    for (int h = 0; h < 4; ++h) {
        float ae = 0.f;
        #pragma unroll
        for (int d = 0; d < 8; ++d) ae += f[d] * q[h * 8 + d];
        float a = asp[h] + adp[h] + ae;
        a = (a > 0.f) ? a : 0.2f * a;
        op[h] = expf(a);
    }
    *(float4*)(wbuf + (size_t)i * 4) = o;
}

// ---------- layer-1 gather in x-space (guard-free padded rows, den fused) ----------
__global__ __launch_bounds__(256)
void k_gather1(const int* __restrict__ row_start, const int* __restrict__ csr_src,
               const float* __restrict__ wbuf, const __bf16* __restrict__ xb,
               __bf16* __restrict__ aggb) {
    int wv = threadIdx.x >> 6;
    int n = blockIdx.x * 4 + wv;
    int lane = threadIdx.x & 63;
    if (n >= N_NODES) return;
    int rs = row_start[n], re = row_start[n + 1];
    float acc[4] = {};
    float den[4] = {};

    for (int i = rs; i < re; i += 8) {
        unsigned short xr[8];
        float4 wr[8];
        #pragma unroll
        for (int p = 0; p < 8; ++p) {
            int sp = csr_src[i + p];
            xr[p] = *(const unsigned short*)(xb + (size_t)sp * 64 + lane);
            wr[p] = *(const float4*)(wbuf + (size_t)(i + p) * 4);
        }
        __builtin_amdgcn_sched_barrier(0);
        #pragma unroll
        for (int p = 0; p < 8; ++p) {
            float xv = (float)*(const __bf16*)&xr[p];
            acc[0] += wr[p].x * xv; den[0] += wr[p].x;
            acc[1] += wr[p].y * xv; den[1] += wr[p].y;
            acc[2] += wr[p].z * xv; den[2] += wr[p].z;
            acc[3] += wr[p].w * xv; den[3] += wr[p].w;
        }
    }
    #pragma unroll
    for (int h = 0; h < 4; ++h)
        aggb[(size_t)n * 256 + h * 64 + lane] = (__bf16)(acc[h] / den[h]);
}

// ---------- layer-2 per-head gather + FUSED decoder UV partials (no zh write) ----------
__global__ __launch_bounds__(256)
void k_gather2h(const int* __restrict__ row_start, const int* __restrict__ csr_src,
                const float* __restrict__ wbuf, const __bf16* __restrict__ xph,
                const float* __restrict__ b2, const float* __restrict__ Mm,
                float* __restrict__ Up, float* __restrict__ Vp) {
    int h = blockIdx.y;
    int wv = threadIdx.x >> 6;
    int n = blockIdx.x * 4 + wv;
    int lane = threadIdx.x & 63;
    if (n >= N_NODES) return;
    int rs = row_start[n], re = row_start[n + 1];
    const __bf16* xbase = xph + (size_t)h * N_NODES * 128 + lane * 2;
    float a0 = 0.f, a1 = 0.f, den = 0.f;

    int i = rs;
    for (; i + 16 <= re; i += 16) {
        unsigned xr[16];
        float wr[16];
        #pragma unroll
        for (int p = 0; p < 16; ++p) {
            int sp = csr_src[i + p];
            wr[p] = wbuf[(size_t)(i + p) * 4 + h];
            xr[p] = *(const unsigned*)(xbase + (size_t)sp * 128);
        }
        __builtin_amdgcn_sched_barrier(0);
        #pragma unroll
        for (int p = 0; p < 16; ++p) {
            __bf16 b0 = *(const __bf16*)&xr[p];
            __bf16 b1v = *((const __bf16*)&xr[p] + 1);
            den += wr[p];
            a0 += wr[p] * (float)b0;
            a1 += wr[p] * (float)b1v;
        }
    }
    for (; i < re; i += 8) {
        unsigned xr[8];
        float wr[8];
        #pragma unroll
        for (int p = 0; p < 8; ++p) {
            int sp = csr_src[i + p];
            wr[p] = wbuf[(size_t)(i + p) * 4 + h];
            xr[p] = *(const unsigned*)(xbase + (size_t)sp * 128);
        }
        __builtin_amdgcn_sched_barrier(0);
        #pragma unroll
        for (int p = 0; p < 8; ++p) {
            __bf16 b0 = *(const __bf16*)&xr[p];
            __bf16 b1v = *((const __bf16*)&xr[p] + 1);
            den += wr[p];
            a0 += wr[p] * (float)b0;
            a1 += wr[p] * (float)b1v;
        }
    }
    float inv = 1.f / den;
    float v0 = a0 * inv + b2[h * 128 + lane * 2];
    float v1 = a1 * inv + b2[h * 128 + lane * 2 + 1];
    v0 = (v0 > 0.f) ? v0 : expm1f(v0);
    v1 = (v1 > 0.f) ? v1 : expm1f(v1);

    // fused decoder: per-head partial U/V (z never hits global)
    const float* m0 = Mm + (h * 128 + lane * 2) * 4;
    const float* n0 = Mm + 2048 + (h * 128 + lane * 2) * 4;
    float up[4], vp[4];
    #pragma unroll
    for (int r = 0; r < 4; ++r) {
        up[r] = v0 * m0[r] + v1 * m0[4 + r];
        vp[r] = v0 * n0[r] + v1 * n0[4 + r];
    }
    #pragma unroll
    for (int off = 32; off; off >>= 1) {
        #pragma unroll
        for (int r = 0; r < 4; ++r) {
            up[r] += __shfl_xor(up[r], off);
            vp[r] += __shfl_xor(vp[r], off);
        }
    }
    if (lane == 0) {
        *(float4*)(Up + ((size_t)h * N_NODES + n) * 4) = make_float4(up[0], up[1], up[2], up[3]);
        *(float4*)(Vp + ((size_t)h * N_NODES + n) * 4) = make_float4(vp[0], vp[1], vp[2], vp[3]);
    }
}

// ---------- per-edge output: sum 4 head-partials + sigmoid ----------
__global__ void k_edge_out(const int* __restrict__ ei, const float* __restrict__ Up,
                           const float* __restrict__ Vp, const float* __restrict__ cvec,
                           float* __restrict__ out) {
    int e = blockIdx.x * 256 + threadIdx.x;
    if (e >= N_EDGES) return;
    int s = ei[e], d = ei[N_EDGES + e];
    float4 u = make_float4(0.f, 0.f, 0.f, 0.f);
    float4 v = make_float4(0.f, 0.f, 0.f, 0.f);
    #pragma unroll
    for (int h = 0; h < 4; ++h) {
        float4 uh = *(const float4*)(Up + ((size_t)h * N_NODES + s) * 4);
        float4 vh = *(const float4*)(Vp + ((size_t)h * N_NODES + d) * 4);
        u.x += uh.x; u.y += uh.y; u.z += uh.z; u.w += uh.w;
        v.x += vh.x; v.y += vh.y; v.z += vh.z; v.w += vh.w;
    }
    float4 c = *(const float4*)cvec;
    float4 o;
    o.x = 1.f / (1.f + expf(-(u.x + v.x + c.x)));
    o.y = 1.f / (1.f + expf(-(u.y + v.y + c.y)));
    o.z = 1.f / (1.f + expf(-(u.z + v.z + c.z)));
    o.w = 1.f / (1.f + expf(-(u.w + v.w + c.w)));
    *(float4*)(out + (size_t)e * 4) = o;
}

extern "C" void kernel_launch(void* const* d_in, const int* in_sizes, int n_in,
                              void* d_out, int out_size, void* d_ws, size_t ws_size,
                              hipStream_t stream) {
    (void)in_sizes; (void)n_in; (void)out_size; (void)ws_size;
    const float* x      = (const float*)d_in[0];
    const int*   ei     = (const int*)d_in[1];
    const float* ef     = (const float*)d_in[2];
    const float* W1     = (const float*)d_in[3];
    const float* a_src1 = (const float*)d_in[4];
    const float* a_dst1 = (const float*)d_in[5];
    const float* We1    = (const float*)d_in[6];
    const float* a_e1   = (const float*)d_in[7];
    const float* b1     = (const float*)d_in[8];
    const float* W2     = (const float*)d_in[9];
    const float* a_src2 = (const float*)d_in[10];
    const float* a_dst2 = (const float*)d_in[11];
    const float* We2    = (const float*)d_in[12];
    const float* a_e2   = (const float*)d_in[13];
    const float* b2     = (const float*)d_in[14];
    const float* Wd1    = (const float*)d_in[15];
    const float* bd1    = (const float*)d_in[16];
    const float* Wd2    = (const float*)d_in[17];
    const float* bd2    = (const float*)d_in[18];
    float* out = (float*)d_out;

    // workspace layout
    float* wbuf   = (float*)d_ws;                            // E_PAD*4
    float* as_    = wbuf + (size_t)E_PAD * 4;                // N*4
    float* ad_    = as_ + N_NODES * 4;                       // N*4
    float* meanf  = ad_ + N_NODES * 4;                       // N*8
    float* q1     = meanf + N_NODES * 8;                     // 32
    float* q2     = q1 + 32;                                 // 32
    float* w1as   = q2 + 32;                                 // 256
    float* w1ad   = w1as + 256;                              // 256
    float* Mm     = w1ad + 256;                              // 4096
    float* cv     = Mm + 4096;                               // 4
    float* Up     = cv + 4;                                  // 4*N*4
    float* Vp     = Up + (size_t)N_NODES * 16;               // 4*N*4
    int* row_start = (int*)(Vp + (size_t)N_NODES * 16);      // 20004
    int* nxt       = row_start + 20004;                      // N
    int* counts    = nxt + N_NODES;                          // N      (zeroed by k_fill)
    int* csr_src   = counts + N_NODES;                       // E_PAD  (zeroed, adjacent)
    int* csr_eid   = csr_src + E_PAD;                        // E_PAD  (-1 by k_fill)
    int* csr_dst   = csr_eid + E_PAD;                        // E_PAD
    __bf16* xb   = (__bf16*)(csr_dst + E_PAD);               // N*64
    __bf16* aggb = xb + (size_t)N_NODES * FIN;               // N*256
    __bf16* z1b  = aggb + (size_t)N_NODES * 256;             // N*512
    __bf16* xph2 = z1b + (size_t)N_NODES * HC;               // N*512 head-major
    __bf16* Wt1  = xph2 + (size_t)N_NODES * HC;              // 512*64
    __bf16* Wt2  = Wt1 + HC * FIN;                           // 512*512

    // ---- prep ----
    k_fill<<<(NZ4 + NM4 + 255) / 256, 256, 0, stream>>>((int4*)counts, (int4*)csr_eid);
    k_count<<<(E_TOT + 255) / 256, 256, 0, stream>>>(ei, counts);
    k_scan<<<1, 1024, 0, stream>>>(counts, row_start, nxt);
    k_scatter<<<(E_TOT + 255) / 256, 256, 0, stream>>>(ei, nxt, csr_src, csr_eid, csr_dst);
    k_mean_csr<<<(N_NODES + 31) / 32, 256, 0, stream>>>(row_start, csr_eid, ef, meanf);
    k_prep_all<<<XB + W1B + W2B + PREPB, 256, 0, stream>>>(x, xb, W1, Wt1, W2, Wt2,
                                                           We1, a_e1, We2, a_e2, q1, q2,
                                                           Wd1, Wd2, bd1, bd2, Mm, cv,
                                                           a_src1, a_dst1, w1as, w1ad);

    const int nblk = (N_NODES + 3) / 4;      // 5000
    const int nby = (N_NODES + 127) / 128;   // 157

    // ---- layer 1 (xp never materialized) ----
    k_nodeab<<<nblk, 256, 0, stream>>>(xb, w1as, w1ad, as_, ad_);
    k_edge_ex<<<(E_PAD + 255) / 256, 256, 0, stream>>>(csr_src, csr_dst, csr_eid, ef, meanf,
                                                       q1, as_, ad_, wbuf);
    k_gather1<<<nblk, 256, 0, stream>>>(row_start, csr_src, wbuf, xb, aggb);
    k_gemm_head<<<dim3(4, nby), 256, 0, stream>>>(aggb, Wt1, b1, z1b, N_NODES);

    // ---- layer 2 (node alphas fused into GEMM epilogue) ----
    k_gemm_bf16<<<nby * 4, 256, 0, stream>>>(z1b, Wt2, xph2, N_NODES, HC,
                                             a_src2, a_dst2, as_, ad_);
    k_edge_ex<<<(E_PAD + 255) / 256, 256, 0, stream>>>(csr_src, csr_dst, csr_eid, ef, meanf,
                                                       q2, as_, ad_, wbuf);
    k_gather2h<<<dim3(nblk, 4), 256, 0, stream>>>(row_start, csr_src, wbuf, xph2, b2,
                                                  Mm, Up, Vp);

    // ---- output ----
    k_edge_out<<<(N_EDGES + 255) / 256, 256, 0, stream>>>(ei, Up, Vp, cv, out);
}

// Round 17
// 224.869 us; speedup vs baseline: 1.4143x; 1.0264x over previous
//
#include <hip/hip_runtime.h>
#include <hip/hip_bf16.h>
#include <math.h>

#define N_NODES 20000
#define N_EDGES 160000
#define FIN 64
#define EDGE_DIM 8
#define H_HEADS 4
#define C_CH 128
#define HC 512
#define NUM_RELS 4
#define E_TOT (N_EDGES + N_NODES)   // 180000
#define E_PAD 320256                // >= sum of per-row 8-padded counts

typedef __bf16 bf16x8 __attribute__((ext_vector_type(8)));
typedef __bf16 bf16x4 __attribute__((ext_vector_type(4)));
typedef float f32x4 __attribute__((ext_vector_type(4)));
typedef unsigned short u16x8 __attribute__((ext_vector_type(8)));

// ---------- custom fill: zero wbuf+counts+csr_src (contiguous), csr_eid = -1 ----------
// zero block: wbuf(4*E_PAD) + counts(N) + csr_src(E_PAD) ints
#define NZ4 ((5 * E_PAD + N_NODES) / 4)   // 405320
#define NM4 (E_PAD / 4)                   // 80064
__global__ void k_fill(int4* __restrict__ zbase, int4* __restrict__ mbase) {
    int tid = blockIdx.x * 256 + threadIdx.x;
    if (tid < NZ4) {
        zbase[tid] = make_int4(0, 0, 0, 0);
    } else if (tid < NZ4 + NM4) {
        mbase[tid - NZ4] = make_int4(-1, -1, -1, -1);
    }
}

// ---------- merged prep: x cvt + tiled W1/W2 transposes + small precomputes ----------
#define NX4 (N_NODES * FIN / 4)          // 320000
#define XB  (NX4 / 256)                  // 1250 (exact)
#define W1B 8                            // W1: 64x512 -> 8 tiles of 64x64
#define W2B 64                           // W2: 512x512 -> 64 tiles
#define PREPB 19
__global__ void k_prep_all(const float* __restrict__ x, __bf16* __restrict__ xb,
                           const float* __restrict__ W1, __bf16* __restrict__ Wt1,
                           const float* __restrict__ W2, __bf16* __restrict__ Wt2,
                           const float* __restrict__ We1, const float* __restrict__ ae1,
                           const float* __restrict__ We2, const float* __restrict__ ae2,
                           float* __restrict__ q1, float* __restrict__ q2,
                           const float* __restrict__ Wd1, const float* __restrict__ Wd2,
                           const float* __restrict__ bd1, const float* __restrict__ bd2,
                           float* __restrict__ M, float* __restrict__ cvec,
                           const float* __restrict__ as1, const float* __restrict__ ad1,
                           float* __restrict__ w1as, float* __restrict__ w1ad) {
    __shared__ float tile[64][65];
    int bid = blockIdx.x;
    int t = threadIdx.x;
    if (bid < XB) {
        int tid = bid * 256 + t;
        float4 v = *(const float4*)(x + (size_t)tid * 4);
        __bf16 o[4] = {(__bf16)v.x, (__bf16)v.y, (__bf16)v.z, (__bf16)v.w};
        *(ushort2*)(xb + (size_t)tid * 4) = *(ushort2*)o;
        *(ushort2*)(xb + (size_t)tid * 4 + 2) = *(ushort2*)(o + 2);
        return;
    }
    if (bid < XB + W1B) {
        int tn = bid - XB;
        int rr = t >> 6, cc = t & 63;
        #pragma unroll
        for (int i = 0; i < 16; ++i) {
            int row = rr * 16 + i;
            tile[row][cc] = W1[(size_t)row * HC + tn * 64 + cc];
        }
        __syncthreads();
        #pragma unroll
        for (int i = 0; i < 16; ++i) {
            int row = rr * 16 + i;
            Wt1[(size_t)(tn * 64 + row) * 64 + cc] = (__bf16)tile[cc][row];
        }
        return;
    }
    if (bid < XB + W1B + W2B) {
        int p2 = bid - XB - W1B;
        int tk = p2 >> 3, tn = p2 & 7;
        int rr = t >> 6, cc = t & 63;
        #pragma unroll
        for (int i = 0; i < 16; ++i) {
            int row = rr * 16 + i;
            tile[row][cc] = W2[(size_t)(tk * 64 + row) * HC + tn * 64 + cc];
        }
        __syncthreads();
        #pragma unroll
        for (int i = 0; i < 16; ++i) {
            int row = rr * 16 + i;
            Wt2[(size_t)(tn * 64 + row) * HC + tk * 64 + cc] = (__bf16)tile[cc][row];
        }
        return;
    }
    int pb = bid - XB - W1B - W2B;     // 0..18
    if (pb == 16) {
        if (t >= 64) return;
        const float* We = (t < 32) ? We1 : We2;
        const float* ae = (t < 32) ? ae1 : ae2;
        float* q = (t < 32) ? q1 : q2;
        int i = t & 31, h = i >> 3, d = i & 7;
        float s = 0.f;
        for (int c = 0; c < 128; ++c) s += We[d * 512 + h * 128 + c] * ae[h * 128 + c];
        q[i] = s;
    } else if (pb == 17 || pb == 18) {
        int h = t >> 6, k = t & 63;
        const float* av = (pb == 17) ? as1 : ad1;
        float* outp = (pb == 17) ? w1as : w1ad;
        float s = 0.f;
        for (int c = 0; c < 128; ++c) s += W1[(size_t)k * HC + h * 128 + c] * av[h * 128 + c];
        outp[h * 64 + k] = s;
    } else {
        int tid = pb * 256 + t;   // < 4096
        int i = tid >> 2, r = tid & 3;
        float s = 0.f;
        for (int k = 0; k < 256; ++k) s += Wd1[i * 256 + k] * Wd2[k * 4 + r];
        M[tid] = s;
        if (tid < 4) {
            float c = 0.f;
            for (int k = 0; k < 256; ++k) c += bd1[k] * Wd2[k * 4 + tid];
            cvec[tid] = c + bd2[tid];
        }
    }
}

// ---------- bf16 MFMA GEMM (layer 2): head-major out + FUSED node alphas ----------
#define LDP 40
__global__ __launch_bounds__(256)
void k_gemm_bf16(const __bf16* __restrict__ A, const __bf16* __restrict__ Bt,
                 __bf16* __restrict__ Ch, int M, int K,
                 const float* __restrict__ a_s2, const float* __restrict__ a_d2,
                 float* __restrict__ as_, float* __restrict__ ad_) {
    __shared__ __bf16 As[128 * LDP];
    __shared__ __bf16 Bs[128 * LDP];

    int nwg = gridDim.x;
    int f = blockIdx.x;
    int q = nwg >> 3, r = nwg & 7;
    int xcd = f & 7, idx = f >> 3;
    int wg = (xcd < r ? xcd * (q + 1) : r * (q + 1) + (xcd - r) * q) + idx;
    int by = wg >> 2, bx = wg & 3;
    int br = by * 128, bc = bx * 128;

    const int t = threadIdx.x;
    const int lane = t & 63;
    const int wid = t >> 6;
    const int wr = wid >> 1, wc = wid & 1;
    const int l15 = lane & 15, lkg = lane >> 4;

    const int srow = t >> 1, shalf = (t & 1) * 16;
    const int agr = br + srow;
    const __bf16* Ap = A + (size_t)agr * K + shalf;
    const __bf16* Bp = Bt + (size_t)(bc + srow) * K + shalf;

    f32x4 acc[4][4] = {};

    for (int k0 = 0; k0 < K; k0 += 32) {
        u16x8 av0 = {}, av1 = {};
        if (agr < M) {
            av0 = *(const u16x8*)(Ap + k0);
            av1 = *(const u16x8*)(Ap + k0 + 8);
        }
        u16x8 bv0 = *(const u16x8*)(Bp + k0);
        u16x8 bv1 = *(const u16x8*)(Bp + k0 + 8);
        *(u16x8*)(As + srow * LDP + shalf) = av0;
        *(u16x8*)(As + srow * LDP + shalf + 8) = av1;
        *(u16x8*)(Bs + srow * LDP + shalf) = bv0;
        *(u16x8*)(Bs + srow * LDP + shalf + 8) = bv1;
        __syncthreads();

        bf16x8 a[4], b[4];
        #pragma unroll
        for (int m = 0; m < 4; ++m)
            a[m] = *(const bf16x8*)(As + (wr * 64 + m * 16 + l15) * LDP + lkg * 8);
        #pragma unroll
        for (int n = 0; n < 4; ++n)
            b[n] = *(const bf16x8*)(Bs + (wc * 64 + n * 16 + l15) * LDP + lkg * 8);
        #pragma unroll
        for (int m = 0; m < 4; ++m)
            #pragma unroll
            for (int n = 0; n < 4; ++n)
                acc[m][n] = __builtin_amdgcn_mfma_f32_16x16x32_bf16(a[m], b[n], acc[m][n], 0, 0, 0);
        __syncthreads();
    }

    // C-write (head-major)
    #pragma unroll
    for (int m = 0; m < 4; ++m) {
        int rbase = br + wr * 64 + m * 16 + lkg * 4;
        #pragma unroll
        for (int n = 0; n < 4; ++n) {
            int lcol = wc * 64 + n * 16 + l15;
            #pragma unroll
            for (int rg = 0; rg < 4; ++rg) {
                int gr = rbase + rg;
                if (gr < M)
                    Ch[((size_t)bx * N_NODES + gr) * 128 + lcol] = (__bf16)acc[m][n][rg];
            }
        }
    }

    // ---- fused alpha_src / alpha_dst for head bx ----
    float as_w[4], ad_w[4];
    #pragma unroll
    for (int n = 0; n < 4; ++n) {
        int col = wc * 64 + n * 16 + l15;
        as_w[n] = a_s2[bx * 128 + col];
        ad_w[n] = a_d2[bx * 128 + col];
    }
    float* sred = (float*)As;   // 512 floats scratch
    #pragma unroll
    for (int m = 0; m < 4; ++m) {
        #pragma unroll
        for (int rg = 0; rg < 4; ++rg) {
            float s = 0.f, d = 0.f;
            #pragma unroll
            for (int n = 0; n < 4; ++n) {
                float c = acc[m][n][rg];
                s += c * as_w[n];
                d += c * ad_w[n];
            }
            #pragma unroll
            for (int off = 1; off <= 8; off <<= 1) {
                s += __shfl_xor(s, off);
                d += __shfl_xor(d, off);
            }
            if (l15 == 0) {
                int lrow = wr * 64 + m * 16 + lkg * 4 + rg;
                sred[lrow * 2 + wc] = s;
                sred[256 + lrow * 2 + wc] = d;
            }
        }
    }
    __syncthreads();
    if (t < 128) {
        int gr = br + t;
        if (gr < M) {
            as_[gr * 4 + bx] = sred[t * 2] + sred[t * 2 + 1];
            ad_[gr * 4 + bx] = sred[256 + t * 2] + sred[256 + t * 2 + 1];
        }
    }
}

// ---------- layer-1 head GEMM: z1[n, h*128+c] = elu(agg[n,h,:]@W1h + b1) ----------
__global__ __launch_bounds__(256)
void k_gemm_head(const __bf16* __restrict__ aggb, const __bf16* __restrict__ Wt1,
                 const float* __restrict__ b1, __bf16* __restrict__ z1b, int M) {
    __shared__ __bf16 As[128 * LDP];
    __shared__ __bf16 Bs[128 * LDP];
    const int h = blockIdx.x;
    const int br = blockIdx.y * 128;

    const int t = threadIdx.x;
    const int lane = t & 63;
    const int wid = t >> 6;
    const int wr = wid >> 1, wc = wid & 1;
    const int l15 = lane & 15, lkg = lane >> 4;

    const int srow = t >> 1, shalf = (t & 1) * 16;
    const int agr = br + srow;
    const __bf16* Ap = aggb + (size_t)agr * 256 + h * 64 + shalf;
    const __bf16* Bp = Wt1 + (size_t)(h * 128 + srow) * 64 + shalf;

    f32x4 acc[4][4] = {};

    #pragma unroll
    for (int k0 = 0; k0 < 64; k0 += 32) {
        u16x8 av0 = {}, av1 = {};
        if (agr < M) {
            av0 = *(const u16x8*)(Ap + k0);
            av1 = *(const u16x8*)(Ap + k0 + 8);
        }
        u16x8 bv0 = *(const u16x8*)(Bp + k0);
        u16x8 bv1 = *(const u16x8*)(Bp + k0 + 8);
        *(u16x8*)(As + srow * LDP + shalf) = av0;
        *(u16x8*)(As + srow * LDP + shalf + 8) = av1;
        *(u16x8*)(Bs + srow * LDP + shalf) = bv0;
        *(u16x8*)(Bs + srow * LDP + shalf + 8) = bv1;
        __syncthreads();

        bf16x8 a[4], b[4];
        #pragma unroll
        for (int m = 0; m < 4; ++m)
            a[m] = *(const bf16x8*)(As + (wr * 64 + m * 16 + l15) * LDP + lkg * 8);
        #pragma unroll
        for (int n = 0; n < 4; ++n)
            b[n] = *(const bf16x8*)(Bs + (wc * 64 + n * 16 + l15) * LDP + lkg * 8);
        #pragma unroll
        for (int m = 0; m < 4; ++m)
            #pragma unroll
            for (int n = 0; n < 4; ++n)
                acc[m][n] = __builtin_amdgcn_mfma_f32_16x16x32_bf16(a[m], b[n], acc[m][n], 0, 0, 0);
        __syncthreads();
    }

    #pragma unroll
    for (int m = 0; m < 4; ++m) {
        int rbase = br + wr * 64 + m * 16 + lkg * 4;
        #pragma unroll
        for (int n = 0; n < 4; ++n) {
            int gcol = h * 128 + wc * 64 + n * 16 + l15;
            float bias = b1[gcol];
            #pragma unroll
            for (int rg = 0; rg < 4; ++rg) {
                int gr = rbase + rg;
                if (gr < M) {
                    float v = acc[m][n][rg] + bias;
                    v = (v > 0.f) ? v : expm1f(v);
                    z1b[(size_t)gr * HC + gcol] = (__bf16)v;
                }
            }
        }
    }
}

// ---------- CSR build (8-padded rows) ----------
__global__ void k_count(const int* __restrict__ ei, int* __restrict__ counts) {
    int e = blockIdx.x * 256 + threadIdx.x;
    if (e >= E_TOT) return;
    int dst = (e < N_EDGES) ? ei[N_EDGES + e] : (e - N_EDGES);
    atomicAdd(counts + dst, 1);
}

__global__ __launch_bounds__(1024)
void k_scan(const int* __restrict__ counts, int* __restrict__ row_start,
            int* __restrict__ nxt) {
    __shared__ int part[1024];
    int t = threadIdx.x;
    int base = t * 20;
    int pre[20];
    int s = 0;
    #pragma unroll
    for (int i = 0; i < 20; ++i) {
        int idx = base + i;
        int c = (idx < N_NODES) ? ((counts[idx] + 7) & ~7) : 0;   // pad to x8
        pre[i] = s; s += c;
    }
    part[t] = s;
    __syncthreads();
    for (int off = 1; off < 1024; off <<= 1) {
        int v = (t >= off) ? part[t - off] : 0;
        __syncthreads();
        part[t] += v;
        __syncthreads();
    }
    int excl = (t == 0) ? 0 : part[t - 1];
    #pragma unroll
    for (int i = 0; i < 20; ++i) {
        int idx = base + i;
        if (idx < N_NODES) { int v = excl + pre[i]; row_start[idx] = v; nxt[idx] = v; }
    }
    if (t == 1023) row_start[N_NODES] = part[1023];
}

__global__ void k_scatter(const int* __restrict__ ei, int* __restrict__ nxt,
                          int* __restrict__ csr_src, int* __restrict__ csr_eid,
                          int* __restrict__ slot_of_e) {
    int e = blockIdx.x * 256 + threadIdx.x;
    if (e >= E_TOT) return;
    int src, dst;
    if (e < N_EDGES) { src = ei[e]; dst = ei[N_EDGES + e]; }
    else             { src = dst = e - N_EDGES; }
    int pos = atomicAdd(nxt + dst, 1);
    csr_src[pos] = src;
    csr_eid[pos] = e;
    slot_of_e[e] = pos;
}

// ---------- self-loop mean edge features ----------
__global__ void k_mean_csr(const int* __restrict__ row_start, const int* __restrict__ csr_eid,
                           const float* __restrict__ ef, float* __restrict__ meanf) {
    int n = blockIdx.x * 32 + (threadIdx.x >> 3);
    int d = threadIdx.x & 7;
    if (n >= N_NODES) return;
    int rs = row_start[n], re = row_start[n + 1];
    float s = 0.f; int c = 0;
    for (int i = rs; i < re; ++i) {
        unsigned eid = (unsigned)csr_eid[i];
        if (eid < N_EDGES) { s += ef[(size_t)eid * 8 + d]; ++c; }
    }
    meanf[n * 8 + d] = s / fmaxf((float)c, 1.f);
}

// ---------- layer-1 node alphas from x ----------
__global__ __launch_bounds__(256)
void k_nodeab(const __bf16* __restrict__ xb, const float* __restrict__ w1as,
              const float* __restrict__ w1ad, float* __restrict__ as_,
              float* __restrict__ ad_) {
    int n = blockIdx.x * 4 + (threadIdx.x >> 6);
    int lane = threadIdx.x & 63;
    if (n >= N_NODES) return;
    float xv = (float)xb[(size_t)n * 64 + lane];
    float s[4], d[4];
    #pragma unroll
    for (int h = 0; h < 4; ++h) {
        s[h] = xv * w1as[h * 64 + lane];
        d[h] = xv * w1ad[h * 64 + lane];
    }
    #pragma unroll
    for (int off = 32; off; off >>= 1) {
        #pragma unroll
        for (int h = 0; h < 4; ++h) {
            s[h] += __shfl_xor(s[h], off);
            d[h] += __shfl_xor(d[h], off);
        }
    }
    if (lane == 0) {
        *(float4*)(as_ + n * 4) = make_float4(s[0], s[1], s[2], s[3]);
        *(float4*)(ad_ + n * 4) = make_float4(d[0], d[1], d[2], d[3]);
    }
}

// ---------- compact per-edge exp(alpha), e-ordered (coalesced ef), scatter to slot ----------
__global__ void k_edge_ex(const int* __restrict__ ei, const int* __restrict__ slot_of_e,
                          const float* __restrict__ ef, const float* __restrict__ meanf,
                          const float* __restrict__ q, const float* __restrict__ as_,
                          const float* __restrict__ ad_, float* __restrict__ wbuf) {
    int e = blockIdx.x * 256 + threadIdx.x;
    if (e >= E_TOT) return;
    int src, dst;
    const float* fe;
    if (e < N_EDGES) { src = ei[e]; dst = ei[N_EDGES + e]; fe = ef + (size_t)e * 8; }
    else             { src = dst = e - N_EDGES; fe = meanf + (size_t)(e - N_EDGES) * 8; }
    float f[8];
    #pragma unroll
    for (int d = 0; d < 8; ++d) f[d] = fe[d];
    float4 asv = *(const float4*)(as_ + src * 4);
    float4 adv = *(const float4*)(ad_ + dst * 4);
    const float* asp = &asv.x;
    const float* adp = &adv.x;
    float4 o;
    float* op = &o.x;
    #pragma unroll
    for (int h = 0; h < 4; ++h) {
        float ae = 0.f;
        #pragma unroll
        for (int d = 0; d < 8; ++d) ae += f[d] * q[h * 8 + d];
        float a = asp[h] + adp[h] + ae;
        a = (a > 0.f) ? a : 0.2f * a;
        op[h] = expf(a);
    }
    *(float4*)(wbuf + (size_t)slot_of_e[e] * 4) = o;
}

// ---------- layer-1 gather in x-space (scalar row bounds, den fused) ----------
__global__ __launch_bounds__(256)
void k_gather1(const int* __restrict__ row_start, const int* __restrict__ csr_src,
               const float* __restrict__ wbuf, const __bf16* __restrict__ xb,
               __bf16* __restrict__ aggb) {
    int wv = threadIdx.x >> 6;
    int n = blockIdx.x * 4 + wv;
    int lane = threadIdx.x & 63;
    if (n >= N_NODES) return;
    int rs = __builtin_amdgcn_readfirstlane(row_start[n]);
    int re = __builtin_amdgcn_readfirstlane(row_start[n + 1]);
    float acc[4] = {};
    float den[4] = {};

    for (int i = rs; i < re; i += 8) {
        unsigned short xr[8];
        float4 wr[8];
        #pragma unroll
        for (int p = 0; p < 8; ++p) {
            int sp = csr_src[i + p];
            xr[p] = *(const unsigned short*)(xb + (size_t)sp * 64 + lane);
            wr[p] = *(const float4*)(wbuf + (size_t)(i + p) * 4);
        }
        __builtin_amdgcn_sched_barrier(0);
        #pragma unroll
        for (int p = 0; p < 8; ++p) {
            float xv = (float)*(const __bf16*)&xr[p];
            acc[0] += wr[p].x * xv; den[0] += wr[p].x;
            acc[1] += wr[p].y * xv; den[1] += wr[p].y;
            acc[2] += wr[p].z * xv; den[2] += wr[p].z;
            acc[3] += wr[p].w * xv; den[3] += wr[p].w;
        }
    }
    #pragma unroll
    for (int h = 0; h < 4; ++h)
        aggb[(size_t)n * 256 + h * 64 + lane] = (__bf16)(acc[h] / den[h]);
}

// ---------- layer-2 per-head gather + FUSED decoder UV (scalar row bounds) ----------
__global__ __launch_bounds__(256)
void k_gather2h(const int* __restrict__ row_start, const int* __restrict__ csr_src,
                const float* __restrict__ wbuf, const __bf16* __restrict__ xph,
                const float* __restrict__ b2, const float* __restrict__ Mm,
                float* __restrict__ Up, float* __restrict__ Vp) {
    int h = blockIdx.y;
    int wv = threadIdx.x >> 6;
    int n = blockIdx.x * 4 + wv;
    int lane = threadIdx.x & 63;
    if (n >= N_NODES) return;
    int rs = __builtin_amdgcn_readfirstlane(row_start[n]);
    int re = __builtin_amdgcn_readfirstlane(row_start[n + 1]);
    const __bf16* xbase = xph + (size_t)h * N_NODES * 128 + lane * 2;
    float a0 = 0.f, a1 = 0.f, den = 0.f;

    int i = rs;
    for (; i + 16 <= re; i += 16) {
        unsigned xr[16];
        float wr[16];
        #pragma unroll
        for (int p = 0; p < 16; ++p) {
            int sp = csr_src[i + p];
            wr[p] = wbuf[(size_t)(i + p) * 4 + h];
            xr[p] = *(const unsigned*)(xbase + (size_t)sp * 128);
        }
        __builtin_amdgcn_sched_barrier(0);
        #pragma unroll
        for (int p = 0; p < 16; ++p) {
            __bf16 b0 = *(const __bf16*)&xr[p];
            __bf16 b1v = *((const __bf16*)&xr[p] + 1);
            den += wr[p];
            a0 += wr[p] * (float)b0;
            a1 += wr[p] * (float)b1v;
        }
    }
    for (; i < re; i += 8) {
        unsigned xr[8];
        float wr[8];
        #pragma unroll
        for (int p = 0; p < 8; ++p) {
            int sp = csr_src[i + p];
            wr[p] = wbuf[(size_t)(i + p) * 4 + h];
            xr[p] = *(const unsigned*)(xbase + (size_t)sp * 128);
        }
        __builtin_amdgcn_sched_barrier(0);
        #pragma unroll
        for (int p = 0; p < 8; ++p) {
            __bf16 b0 = *(const __bf16*)&xr[p];
            __bf16 b1v = *((const __bf16*)&xr[p] + 1);
            den += wr[p];
            a0 += wr[p] * (float)b0;
            a1 += wr[p] * (float)b1v;
        }
    }
    float inv = 1.f / den;
    float v0 = a0 * inv + b2[h * 128 + lane * 2];
    float v1 = a1 * inv + b2[h * 128 + lane * 2 + 1];
    v0 = (v0 > 0.f) ? v0 : expm1f(v0);
    v1 = (v1 > 0.f) ? v1 : expm1f(v1);

    // fused decoder: per-head partial U/V
    const float* m0 = Mm + (h * 128 + lane * 2) * 4;
    const float* n0 = Mm + 2048 + (h * 128 + lane * 2) * 4;
    float up[4], vp[4];
    #pragma unroll
    for (int r = 0; r < 4; ++r) {
        up[r] = v0 * m0[r] + v1 * m0[4 + r];
        vp[r] = v0 * n0[r] + v1 * n0[4 + r];
    }
    #pragma unroll
    for (int off = 32; off; off >>= 1) {
        #pragma unroll
        for (int r = 0; r < 4; ++r) {
            up[r] += __shfl_xor(up[r], off);
            vp[r] += __shfl_xor(vp[r], off);
        }
    }
    if (lane == 0) {
        *(float4*)(Up + ((size_t)h * N_NODES + n) * 4) = make_float4(up[0], up[1], up[2], up[3]);
        *(float4*)(Vp + ((size_t)h * N_NODES + n) * 4) = make_float4(vp[0], vp[1], vp[2], vp[3]);
    }
}

// ---------- per-edge output: sum 4 head-partials + sigmoid ----------
__global__ void k_edge_out(const int* __restrict__ ei, const float* __restrict__ Up,
                           const float* __restrict__ Vp, const float* __restrict__ cvec,
                           float* __restrict__ out) {
    int e = blockIdx.x * 256 + threadIdx.x;
    if (e >= N_EDGES) return;
    int s = ei[e], d = ei[N_EDGES + e];
    float4 u = make_float4(0.f, 0.f, 0.f, 0.f);
    float4 v = make_float4(0.f, 0.f, 0.f, 0.f);
    #pragma unroll
    for (int h = 0; h < 4; ++h) {
        float4 uh = *(const float4*)(Up + ((size_t)h * N_NODES + s) * 4);
        float4 vh = *(const float4*)(Vp + ((size_t)h * N_NODES + d) * 4);
        u.x += uh.x; u.y += uh.y; u.z += uh.z; u.w += uh.w;
        v.x += vh.x; v.y += vh.y; v.z += vh.z; v.w += vh.w;
    }
    float4 c = *(const float4*)cvec;
    float4 o;
    o.x = 1.f / (1.f + expf(-(u.x + v.x + c.x)));
    o.y = 1.f / (1.f + expf(-(u.y + v.y + c.y)));
    o.z = 1.f / (1.f + expf(-(u.z + v.z + c.z)));
    o.w = 1.f / (1.f + expf(-(u.w + v.w + c.w)));
    *(float4*)(out + (size_t)e * 4) = o;
}

extern "C" void kernel_launch(void* const* d_in, const int* in_sizes, int n_in,
                              void* d_out, int out_size, void* d_ws, size_t ws_size,
                              hipStream_t stream) {
    (void)in_sizes; (void)n_in; (void)out_size; (void)ws_size;
    const float* x      = (const float*)d_in[0];
    const int*   ei     = (const int*)d_in[1];
    const float* ef     = (const float*)d_in[2];
    const float* W1     = (const float*)d_in[3];
    const float* a_src1 = (const float*)d_in[4];
    const float* a_dst1 = (const float*)d_in[5];
    const float* We1    = (const float*)d_in[6];
    const float* a_e1   = (const float*)d_in[7];
    const float* b1     = (const float*)d_in[8];
    const float* W2     = (const float*)d_in[9];
    const float* a_src2 = (const float*)d_in[10];
    const float* a_dst2 = (const float*)d_in[11];
    const float* We2    = (const float*)d_in[12];
    const float* a_e2   = (const float*)d_in[13];
    const float* b2     = (const float*)d_in[14];
    const float* Wd1    = (const float*)d_in[15];
    const float* bd1    = (const float*)d_in[16];
    const float* Wd2    = (const float*)d_in[17];
    const float* bd2    = (const float*)d_in[18];
    float* out = (float*)d_out;

    // workspace layout: [zero block: wbuf | counts | csr_src][-1 block: csr_eid][rest]
    float* wbuf    = (float*)d_ws;                           // E_PAD*4
    int* counts    = (int*)(wbuf + (size_t)E_PAD * 4);       // N
    int* csr_src   = counts + N_NODES;                       // E_PAD
    int* csr_eid   = csr_src + E_PAD;                        // E_PAD (-1 by k_fill)
    int* slot_of_e = csr_eid + E_PAD;                        // E_TOT
    int* row_start = slot_of_e + E_TOT;                      // 20004
    int* nxt       = row_start + 20004;                      // N
    float* as_    = (float*)(nxt + N_NODES);                 // N*4
    float* ad_    = as_ + N_NODES * 4;                       // N*4
    float* meanf  = ad_ + N_NODES * 4;                       // N*8
    float* q1     = meanf + N_NODES * 8;                     // 32
    float* q2     = q1 + 32;                                 // 32
    float* w1as   = q2 + 32;                                 // 256
    float* w1ad   = w1as + 256;                              // 256
    float* Mm     = w1ad + 256;                              // 4096
    float* cv     = Mm + 4096;                               // 4
    float* Up     = cv + 4;                                  // 4*N*4
    float* Vp     = Up + (size_t)N_NODES * 16;               // 4*N*4
    __bf16* xb   = (__bf16*)(Vp + (size_t)N_NODES * 16);     // N*64
    __bf16* aggb = xb + (size_t)N_NODES * FIN;               // N*256
    __bf16* z1b  = aggb + (size_t)N_NODES * 256;             // N*512
    __bf16* xph2 = z1b + (size_t)N_NODES * HC;               // N*512 head-major
    __bf16* Wt1  = xph2 + (size_t)N_NODES * HC;              // 512*64
    __bf16* Wt2  = Wt1 + HC * FIN;                           // 512*512

    // ---- prep ----
    k_fill<<<(NZ4 + NM4 + 255) / 256, 256, 0, stream>>>((int4*)wbuf, (int4*)csr_eid);
    k_count<<<(E_TOT + 255) / 256, 256, 0, stream>>>(ei, counts);
    k_scan<<<1, 1024, 0, stream>>>(counts, row_start, nxt);
    k_scatter<<<(E_TOT + 255) / 256, 256, 0, stream>>>(ei, nxt, csr_src, csr_eid, slot_of_e);
    k_mean_csr<<<(N_NODES + 31) / 32, 256, 0, stream>>>(row_start, csr_eid, ef, meanf);
    k_prep_all<<<XB + W1B + W2B + PREPB, 256, 0, stream>>>(x, xb, W1, Wt1, W2, Wt2,
                                                           We1, a_e1, We2, a_e2, q1, q2,
                                                           Wd1, Wd2, bd1, bd2, Mm, cv,
                                                           a_src1, a_dst1, w1as, w1ad);

    const int nblk = (N_NODES + 3) / 4;      // 5000
    const int nby = (N_NODES + 127) / 128;   // 157

    // ---- layer 1 (xp never materialized) ----
    k_nodeab<<<nblk, 256, 0, stream>>>(xb, w1as, w1ad, as_, ad_);
    k_edge_ex<<<(E_TOT + 255) / 256, 256, 0, stream>>>(ei, slot_of_e, ef, meanf,
                                                       q1, as_, ad_, wbuf);
    k_gather1<<<nblk, 256, 0, stream>>>(row_start, csr_src, wbuf, xb, aggb);
    k_gemm_head<<<dim3(4, nby), 256, 0, stream>>>(aggb, Wt1, b1, z1b, N_NODES);

    // ---- layer 2 (node alphas fused into GEMM epilogue) ----
    k_gemm_bf16<<<nby * 4, 256, 0, stream>>>(z1b, Wt2, xph2, N_NODES, HC,
                                             a_src2, a_dst2, as_, ad_);
    k_edge_ex<<<(E_TOT + 255) / 256, 256, 0, stream>>>(ei, slot_of_e, ef, meanf,
                                                       q2, as_, ad_, wbuf);
    k_gather2h<<<dim3(nblk, 4), 256, 0, stream>>>(row_start, csr_src, wbuf, xph2, b2,
                                                  Mm, Up, Vp);

    // ---- output ----
    k_edge_out<<<(N_EDGES + 255) / 256, 256, 0, stream>>>(ei, Up, Vp, cv, out);
}